// Round 10
// baseline (660.735 us; speedup 1.0000x reference)
//
#include <hip/hip_runtime.h>
#include <hip/hip_bf16.h>

// Problem constants
#define B_ 128
#define S_ 128
#define W_ 16
#define V_ 128
#define H_ 512
#define L_ 64

typedef _Float16 f16x8 __attribute__((ext_vector_type(8)));
typedef float f32x4 __attribute__((ext_vector_type(4)));

__device__ __forceinline__ float sigm(float v) { return 1.0f / (1.0f + __expf(-v)); }
__device__ __forceinline__ float tanhf_(float v) { return 1.0f - 2.0f / (1.0f + __expf(2.0f * v)); }

__device__ __forceinline__ unsigned short f16bits(_Float16 h) {
    return __builtin_bit_cast(unsigned short, h);
}

// ---------------------------------------------------------------------------
// Workspace layout (bytes):
//   hbuf  u32 packed(hi,lo) [par2][dir2][128][512] @ 0        (1048576)
//   slots (dead)                                   @ 1048576  (16384)
//   flag  (dead)                                   @ 1064960  (64)
//   xhi   u16 [128][128][128]                      @ 1065024  (4194304)
//   xlo   u16 [128][128][128]                      @ 5259328  (4194304)
//   whalf f16 [1966080]                            @ 9453632  (3932160)
//         [whhf 786432 | whhb 786432 | wihf 196608 | wihb 196608]
//   smallF f32 [71745]                             @ 13385792 (287040)
//         [bihf 1536|bhhf 1536|bihb 1536|bhhb 1536|wlin 65536|blin 64|fg 1]
//   Ycat  f16 [128][128][1024]                     @ 13672832 (33554432)
//   wlinh f16 [64][1024]                           @ 47227264 (131072)
//   wlinl f16 [64][1024]                           @ 47358336 (131072) -> ends 47489408
// ---------------------------------------------------------------------------
#define OFF_SLOT  1048576
#define OFF_FLAG  1064960
#define OFF_XHI   1065024
#define OFF_XLO   5259328
#define OFF_WH    9453632
#define OFF_SMALL 13385792
#define OFF_YCAT  13672832
#define OFF_WLH   47227264
#define OFF_WLL   47358336

// ---------------------------------------------------------------------------
// R19: ALL prep fused into ONE dispatch; dtype flag computed per-block
// (deterministic ballot vote over the same 256 words of Whhf — replaces the
// separate detect_kernel launch).
//   bid <  7680           : whalf canonicalization (fp16 RTN)
//   bid <  7961           : biases/W_lin/b_lin/forget -> fp32
//   bid <  8217           : W_lin hi/lo f16 planes
//   else (8192 blocks)    : FOFE -> xhi/xlo
// ---------------------------------------------------------------------------
__global__ void prep_all(const void* __restrict__ whhf, const void* __restrict__ whhb,
                         const void* __restrict__ wihf, const void* __restrict__ wihb,
                         const void* __restrict__ bihf, const void* __restrict__ bhhf,
                         const void* __restrict__ bihb, const void* __restrict__ bhhb,
                         const void* __restrict__ wlin, const void* __restrict__ blin,
                         const void* __restrict__ fgp, const int* __restrict__ chars,
                         _Float16* __restrict__ whalf, float* __restrict__ smallF,
                         _Float16* __restrict__ whi, _Float16* __restrict__ wlo,
                         unsigned short* __restrict__ xhi, unsigned short* __restrict__ xlo) {
    const int bid = blockIdx.x;
    const int tid = threadIdx.x;
    const int wave = tid >> 6;
    const int lane = tid & 63;

    // ---- per-block dtype vote (identical inputs -> identical result) ----
    __shared__ int wv[4];
    {
        unsigned word = ((const unsigned*)whhf)[tid];
        unsigned e = (word >> 7) & 0xFFu;
        unsigned long long m = __ballot(e >= 64u && e <= 126u);
        if (lane == 0) wv[wave] = __popcll(m);
    }
    __syncthreads();
    const int fl = (wv[0] + wv[1] + wv[2] + wv[3] >= 160) ? 1 : 0;  // 1 = bf16

    if (bid < 7680) {
        int i = bid * 256 + tid;  // 1966080 exactly
        const void* src;
        int off;
        if (i < 786432)       { src = whhf; off = i; }
        else if (i < 1572864) { src = whhb; off = i - 786432; }
        else if (i < 1769472) { src = wihf; off = i - 1572864; }
        else                  { src = wihb; off = i - 1769472; }
        float v = fl ? __bfloat162float(((const __hip_bfloat16*)src)[off])
                     : ((const float*)src)[off];
        whalf[i] = (_Float16)v;
    } else if (bid < 7961) {
        int i = (bid - 7680) * 256 + tid;
        if (i >= 71745) return;
        const void* src;
        int off;
        if (i < 1536)       { src = bihf; off = i; }
        else if (i < 3072)  { src = bhhf; off = i - 1536; }
        else if (i < 4608)  { src = bihb; off = i - 3072; }
        else if (i < 6144)  { src = bhhb; off = i - 4608; }
        else if (i < 71680) { src = wlin; off = i - 6144; }
        else if (i < 71744) { src = blin; off = i - 71680; }
        else                { src = fgp;  off = 0; }
        float v = fl ? __bfloat162float(((const __hip_bfloat16*)src)[off])
                     : ((const float*)src)[off];
        smallF[i] = v;
    } else if (bid < 8217) {
        int i = (bid - 7961) * 256 + tid;  // 65536
        float v = fl ? __bfloat162float(((const __hip_bfloat16*)wlin)[i])
                     : ((const float*)wlin)[i];
        _Float16 hi = (_Float16)v;
        whi[i] = hi;
        wlo[i] = (_Float16)(v - (float)hi);
    } else {
        // FOFE: 2 positions per block
        __shared__ int cS[2][W_];
        const int fb = bid - 8217;
        int sub = tid >> 7;
        int v = tid & 127;
        int bi = fb * 2 + sub;  // b*S + s
        if (v < W_) cS[sub][v] = chars[bi * W_ + v];
        __syncthreads();
        float f = fl ? __bfloat162float(*(const __hip_bfloat16*)fgp)
                     : *(const float*)fgp;
        float wt[W_];
        float cur = 1.0f;
#pragma unroll
        for (int w = W_ - 1; w >= 0; --w) {
            bool m = (cS[sub][w] != 0);
            wt[w] = m ? cur : 0.0f;
            if (m) cur *= f;
        }
        float acc = 0.0f;
#pragma unroll
        for (int w = 0; w < W_; ++w) acc += (cS[sub][w] == v) ? wt[w] : 0.0f;
        _Float16 hi = (_Float16)acc;
        _Float16 lo = (_Float16)(acc - (float)hi);
        xhi[(size_t)bi * V_ + v] = f16bits(hi);
        xlo[(size_t)bi * V_ + v] = f16bits(lo);
    }
}

// ---------------------------------------------------------------------------
// Persistent bidirectional GRU.
// R19 = R18 champion (tagged fire-and-forget exchange, LDS double-buffer,
// single barrier) + x DIRECT-TO-REGISTER (R17-proven benign path):
//   - Each lane loads its own x fragments (x[batch=col][kx*32+quad*8..])
//     as plain cached loads, issued BEFORE the volley loads. vmcnt is FIFO,
//     so the 24 x-MFMAs wait only on the x loads (vmcnt(16)) and execute in
//     the volley's ~1-RT shadow. x is gone from LDS staging entirely.
//   - t=0: h(0)=0, so the whole h path (volley/stage/barrier/96 h-MFMAs)
//     is skipped uniformly; acc = x-part only.
//   - Volley protocol unchanged from R16/R18 (round-1 issue hoisted; the
//     validate loop re-loads only stale words).
// ---------------------------------------------------------------------------
__launch_bounds__(256, 1)
__global__ void gru_kernel(const int* __restrict__ lengths,
                           const _Float16* __restrict__ wh,
                           const float* __restrict__ biasF,
                           const unsigned short* __restrict__ xhi,
                           const unsigned short* __restrict__ xlo,
                           unsigned* __restrict__ hbuf,
                           _Float16* __restrict__ Ycat) {
    constexpr int RSTR = 656;  // 640 + 16 pad halves (0 conflicts measured r5/r7)
    __shared__ _Float16 Ahi[2][16 * RSTR];
    __shared__ _Float16 Alo[2][16 * RSTR];
    __shared__ int lenS[16];

    const int tid = threadIdx.x;
    const int chain = blockIdx.x & 15;
    const int blk = blockIdx.x >> 4;    // 0..7
    const int d = chain & 1;
    const int bg = chain >> 1;
    const int b0 = bg * 16;
    const int wave = tid >> 6;          // 0..3
    const int lane = tid & 63;
    const int quad = lane >> 4;
    const int col = lane & 15;
    const int j0w = (blk * 4 + wave) * 16;  // 0..496

    const _Float16* Whh = wh + (d ? 786432 : 0);
    const _Float16* Wih = wh + 1572864 + (d ? 196608 : 0);
    const float* bih = biasF + (d ? 3072 : 0);
    const float* bhh = biasF + 1536 + (d ? 3072 : 0);

    if (tid < 16) lenS[tid] = lengths[b0 + tid];
    __syncthreads();

    const int g_r = j0w + col;  // r row; z = 512+g_r; n = 1024+g_r

    // Persistent B fragments: lane holds W[g][kk*32 + quad*8 + 0..7]
    f16x8 br[20], bz[20], bn[20];
#pragma unroll
    for (int kk = 0; kk < 16; ++kk) {
        int k = kk * 32 + quad * 8;
        br[kk] = *(const f16x8*)(Whh + (size_t)(g_r)*H_ + k);
        bz[kk] = *(const f16x8*)(Whh + (size_t)(512 + g_r) * H_ + k);
        bn[kk] = *(const f16x8*)(Whh + (size_t)(1024 + g_r) * H_ + k);
    }
#pragma unroll
    for (int kk = 16; kk < 20; ++kk) {
        int k = (kk - 16) * 32 + quad * 8;
        br[kk] = *(const f16x8*)(Wih + (size_t)(g_r)*V_ + k);
        bz[kk] = *(const f16x8*)(Wih + (size_t)(512 + g_r) * V_ + k);
        bn[kk] = *(const f16x8*)(Wih + (size_t)(1024 + g_r) * V_ + k);
    }

    const float bias_r = bih[g_r] + bhh[g_r];
    const float bias_z = bih[512 + g_r] + bhh[512 + g_r];
    const float bihn = bih[1024 + g_r];
    const float bhhn = bhh[1024 + g_r];

    int len4[4];
#pragma unroll
    for (int i = 0; i < 4; ++i) len4[i] = lenS[quad * 4 + i];
    const int maxlen = lenS[0];  // lengths sorted descending
    const int lenC = lenS[col];  // batch 'col' length (A-row batch for x)

    float h_own[4] = {0.f, 0.f, 0.f, 0.f};  // fp32 master state (b=quad*4+i, j=col)

    const unsigned long long tagMsk = (1ULL << 16) | (1ULL << 48);

    for (int t = 0; t < S_; ++t) {
        if (t < maxlen) {
            const int par = t & 1;

            // ---- x fragments: direct plain loads (L2-resident, RO) ----
            const int sxc = d ? max(0, lenC - 1 - t) : t;
            const unsigned short* xrh =
                xhi + ((size_t)(b0 + col) * S_ + sxc) * V_ + quad * 8;
            const unsigned short* xrl =
                xlo + ((size_t)(b0 + col) * S_ + sxc) * V_ + quad * 8;
            int4 xh4[4], xl4[4];
#pragma unroll
            for (int kx = 0; kx < 4; ++kx) {
                xh4[kx] = *(const int4*)(xrh + kx * 32);
                xl4[kx] = *(const int4*)(xrl + kx * 32);
            }

            // ---- h volley round 1: issue 16 relaxed agent u64 loads ----
            unsigned* hrp = hbuf + ((size_t)(par * 2 + d) * B_ + b0) * H_;
            unsigned long long hv[16];
            if (t > 0) {
#pragma unroll
                for (int i = 0; i < 16; ++i)
                    hv[i] = __hip_atomic_load(
                        (const unsigned long long*)(hrp + (size_t)i * H_ + tid * 2),
                        __ATOMIC_RELAXED, __HIP_MEMORY_SCOPE_AGENT);
            }

            // ---- x-MFMAs: execute in the volley's flight shadow ----
            f32x4 accr = {0.f, 0.f, 0.f, 0.f};
            f32x4 accz = {0.f, 0.f, 0.f, 0.f};
            f32x4 acchn = {0.f, 0.f, 0.f, 0.f};
            f32x4 accxn = {0.f, 0.f, 0.f, 0.f};
#pragma unroll
            for (int kx = 0; kx < 4; ++kx) {
                f16x8 ah = __builtin_bit_cast(f16x8, xh4[kx]);
                f16x8 al = __builtin_bit_cast(f16x8, xl4[kx]);
                accr = __builtin_amdgcn_mfma_f32_16x16x32_f16(ah, br[16 + kx], accr, 0, 0, 0);
                accr = __builtin_amdgcn_mfma_f32_16x16x32_f16(al, br[16 + kx], accr, 0, 0, 0);
                accz = __builtin_amdgcn_mfma_f32_16x16x32_f16(ah, bz[16 + kx], accz, 0, 0, 0);
                accz = __builtin_amdgcn_mfma_f32_16x16x32_f16(al, bz[16 + kx], accz, 0, 0, 0);
                accxn = __builtin_amdgcn_mfma_f32_16x16x32_f16(ah, bn[16 + kx], accxn, 0, 0, 0);
                accxn = __builtin_amdgcn_mfma_f32_16x16x32_f16(al, bn[16 + kx], accxn, 0, 0, 0);
            }

            if (t > 0) {
                // ---- volley validate: re-load only stale words ----
                const unsigned te = ((((unsigned)(t - 1)) >> 1) & 1u) ^ 1u;
                const unsigned long long tagPat =
                    ((unsigned long long)te << 16) | ((unsigned long long)te << 48);
                unsigned pend = 0xFFFFu;
                unsigned round = 0;
                while (true) {
                    unsigned np = 0;
#pragma unroll
                    for (int i = 0; i < 16; ++i)
                        if ((pend & (1u << i)) && (hv[i] & tagMsk) != tagPat) np |= (1u << i);
                    if (!np) break;
#pragma unroll
                    for (int i = 0; i < 16; ++i)
                        if (np & (1u << i))
                            hv[i] = __hip_atomic_load(
                                (const unsigned long long*)(hrp + (size_t)i * H_ + tid * 2),
                                __ATOMIC_RELAXED, __HIP_MEMORY_SCOPE_AGENT);
                    pend = np;
                    ++round;
                    if (round > 4u) __builtin_amdgcn_s_sleep(1);
                    if ((round & 31u) == 31u)  // stale-L2 insurance; free if unused
                        __builtin_amdgcn_fence(__ATOMIC_ACQUIRE, "agent");
                    if (round > 400000u) break;  // malfunction -> visible failure
                }

                // ---- unpack h (clear tag bits) and stage into LDS[par] ----
#pragma unroll
                for (int i = 0; i < 16; ++i) {
                    unsigned p0 = (unsigned)hv[i];
                    unsigned p1 = (unsigned)(hv[i] >> 32);
                    unsigned hi2 = (p0 & 0xffffu) | (p1 << 16);
                    unsigned lo2 = ((p0 >> 16) | (p1 & 0xffff0000u)) & ~0x00010001u;
                    *(unsigned*)&Ahi[par][i * RSTR + tid * 2] = hi2;
                    *(unsigned*)&Alo[par][i * RSTR + tid * 2] = lo2;
                }
                __syncthreads();  // A: h staging complete (only barrier per step)

                // ---- h-MFMAs ----
                const _Float16* arh = &Ahi[par][col * RSTR + quad * 8];
                const _Float16* arl = &Alo[par][col * RSTR + quad * 8];
#pragma unroll
                for (int kk = 0; kk < 16; ++kk) {
                    f16x8 ah = *(const f16x8*)(arh + kk * 32);
                    f16x8 al = *(const f16x8*)(arl + kk * 32);
                    accr = __builtin_amdgcn_mfma_f32_16x16x32_f16(ah, br[kk], accr, 0, 0, 0);
                    accr = __builtin_amdgcn_mfma_f32_16x16x32_f16(al, br[kk], accr, 0, 0, 0);
                    accz = __builtin_amdgcn_mfma_f32_16x16x32_f16(ah, bz[kk], accz, 0, 0, 0);
                    accz = __builtin_amdgcn_mfma_f32_16x16x32_f16(al, bz[kk], accz, 0, 0, 0);
                    acchn = __builtin_amdgcn_mfma_f32_16x16x32_f16(ah, bn[kk], acchn, 0, 0, 0);
                    acchn = __builtin_amdgcn_mfma_f32_16x16x32_f16(al, bn[kk], acchn, 0, 0, 0);
                }
            }

            // ---- gates + state update + tagged h stores (fire-and-forget) ----
            unsigned* hwp = hbuf + ((size_t)((1 - par) * 2 + d) * B_ + b0) * H_;
            const unsigned tg = ((((unsigned)t) >> 1) & 1u) ^ 1u;
            float yv[4];
            int so4[4];
#pragma unroll
            for (int i = 0; i < 4; ++i) {
                int bl = quad * 4 + i;
                float r = sigm(accr[i] + bias_r);
                float zg = sigm(accz[i] + bias_z);
                float ng = tanhf_((accxn[i] + bihn) + r * (acchn[i] + bhhn));
                float hcand = (1.0f - zg) * ng + zg * h_own[i];
                bool m = (t < len4[i]);
                yv[i] = m ? hcand : 0.0f;
                h_own[i] = m ? hcand : h_own[i];
                _Float16 hhi = (_Float16)h_own[i];
                _Float16 hlo = (_Float16)(h_own[i] - (float)hhi);
                unsigned packed = (unsigned)f16bits(hhi) |
                                  ((((unsigned)f16bits(hlo) & 0xFFFEu) | tg) << 16);
                __hip_atomic_store(hwp + (size_t)bl * H_ + j0w + col, packed,
                                   __ATOMIC_RELAXED, __HIP_MEMORY_SCOPE_AGENT);
                so4[i] = (d && m) ? (len4[i] - 1 - t) : t;
            }
            // ---- Ycat stores: drain overlaps peers' polling ----
#pragma unroll
            for (int i = 0; i < 4; ++i) {
                int bl = quad * 4 + i;
                Ycat[((size_t)(b0 + bl) * S_ + so4[i]) * 1024 + d * 512 + j0w + col] =
                    (_Float16)yv[i];
            }
        } else {
            // whole group masked: zeros at s_out = t; no exchange traffic
#pragma unroll
            for (int i = 0; i < 4; ++i) {
                int bl = quad * 4 + i;
                Ycat[((size_t)(b0 + bl) * S_ + t) * 1024 + d * 512 + j0w + col] = (_Float16)0.0f;
            }
        }
    }
}

// ---------------------------------------------------------------------------
// Final linear as MFMA GEMM: out[pos,l] = blin[l] + sum_c Y[pos,c]*W[l,c].
// [16384 x 1024] x [1024 x 64]. Block = 256 thr (4 waves), covers 64 pos;
// wave covers 16 pos x 64 l (4 n-tiles). A-frags load directly from Ycat
// (f16x8, layout = verified GRU operand pattern); W as hi/lo f16 planes
// (exact fp32 reconstruction). 256 MFMA/wave; grid 256.
// ---------------------------------------------------------------------------
__launch_bounds__(256, 1)
__global__ void lin_kernel(const _Float16* __restrict__ Ycat,
                           const _Float16* __restrict__ Whi,
                           const _Float16* __restrict__ Wlo,
                           const float* __restrict__ blinF,
                           float* __restrict__ out) {
    const int tid = threadIdx.x;
    const int wave = tid >> 6;
    const int lane = tid & 63;
    const int quad = lane >> 4;
    const int col = lane & 15;
    const int pos0 = blockIdx.x * 64 + wave * 16;

    const _Float16* arow = Ycat + (size_t)(pos0 + col) * 1024 + quad * 8;

    f32x4 acc[4] = {{0.f, 0.f, 0.f, 0.f}, {0.f, 0.f, 0.f, 0.f},
                    {0.f, 0.f, 0.f, 0.f}, {0.f, 0.f, 0.f, 0.f}};
#pragma unroll 4
    for (int c = 0; c < 1024; c += 32) {
        f16x8 a = *(const f16x8*)(arow + c);
#pragma unroll
        for (int nt = 0; nt < 4; ++nt) {
            const size_t wo = (size_t)(nt * 16 + col) * 1024 + c + quad * 8;
            f16x8 bh = *(const f16x8*)(Whi + wo);
            f16x8 bl = *(const f16x8*)(Wlo + wo);
            acc[nt] = __builtin_amdgcn_mfma_f32_16x16x32_f16(a, bh, acc[nt], 0, 0, 0);
            acc[nt] = __builtin_amdgcn_mfma_f32_16x16x32_f16(a, bl, acc[nt], 0, 0, 0);
        }
    }
    // C layout: row = quad*4 + reg (pos), col = lane&15 (l within n-tile)
#pragma unroll
    for (int nt = 0; nt < 4; ++nt) {
        int l = nt * 16 + col;
        float bias = blinF[l];
#pragma unroll
        for (int r = 0; r < 4; ++r) {
            int pos = pos0 + quad * 4 + r;
            out[(size_t)pos * L_ + l] = acc[nt][r] + bias;
        }
    }
}

extern "C" void kernel_launch(void* const* d_in, const int* in_sizes, int n_in,
                              void* d_out, int out_size, void* d_ws, size_t ws_size,
                              hipStream_t stream) {
    const int* chars = (const int*)d_in[0];
    const int* lengths = (const int*)d_in[1];
    const void* forget = d_in[2];
    const void* Wihf = d_in[3];
    const void* Whhf = d_in[4];
    const void* bihf = d_in[5];
    const void* bhhf = d_in[6];
    const void* Wihb = d_in[7];
    const void* Whhb = d_in[8];
    const void* bihb = d_in[9];
    const void* bhhb = d_in[10];
    const void* Wlin = d_in[11];
    const void* blin = d_in[12];
    float* out = (float*)d_out;

    char* ws = (char*)d_ws;
    unsigned* hbuf = (unsigned*)(ws + 0);
    unsigned short* xhi = (unsigned short*)(ws + OFF_XHI);
    unsigned short* xlo = (unsigned short*)(ws + OFF_XLO);
    _Float16* whalf = (_Float16*)(ws + OFF_WH);
    float* smallF = (float*)(ws + OFF_SMALL);
    _Float16* Ycat = (_Float16*)(ws + OFF_YCAT);
    _Float16* wlh = (_Float16*)(ws + OFF_WLH);
    _Float16* wll = (_Float16*)(ws + OFF_WLL);

    // zero h state only (both parities, tag bits = 0)
    (void)hipMemsetAsync(ws, 0, 1048576, stream);

    // fused prep: whalf (7680) + small (281) + wlin planes (256) + fofe (8192)
    hipLaunchKernelGGL(prep_all, dim3(16409), dim3(256), 0, stream,
                       Whhf, Whhb, Wihf, Wihb, bihf, bhhf, bihb, bhhb,
                       Wlin, blin, forget, chars,
                       whalf, smallF, wlh, wll, xhi, xlo);

    // 16 chains x 8 blocks x 256 threads; tagged fire-and-forget exchange.
    hipLaunchKernelGGL(gru_kernel, dim3(128), dim3(256), 0, stream,
                       lengths, whalf, smallF, xhi, xlo, hbuf, Ycat);

    // MFMA GEMM epilogue: 256 blocks x 64 pos.
    hipLaunchKernelGGL(lin_kernel, dim3(256), dim3(256), 0, stream,
                       Ycat, wlh, wll, smallF + 71680, out);
}

// Round 11
// 605.842 us; speedup vs baseline: 1.0906x; 1.0906x over previous
//
#include <hip/hip_runtime.h>
#include <hip/hip_bf16.h>

// Problem constants
#define B_ 128
#define S_ 128
#define W_ 16
#define V_ 128
#define H_ 512
#define L_ 64

typedef _Float16 f16x8 __attribute__((ext_vector_type(8)));
typedef float f32x4 __attribute__((ext_vector_type(4)));

__device__ __forceinline__ float sigm(float v) { return 1.0f / (1.0f + __expf(-v)); }
__device__ __forceinline__ float tanhf_(float v) { return 1.0f - 2.0f / (1.0f + __expf(2.0f * v)); }

__device__ __forceinline__ unsigned short f16bits(_Float16 h) {
    return __builtin_bit_cast(unsigned short, h);
}

// ---------------------------------------------------------------------------
// Workspace layout (bytes):
//   hbuf  u32 packed(hi,lo) [par2][dir2][128][512] @ 0        (1048576)
//   slots (dead)                                   @ 1048576  (16384)
//   flag  (dead)                                   @ 1064960  (64)
//   xhi   u16 [128][128][128]                      @ 1065024  (4194304)
//   xlo   u16 [128][128][128]                      @ 5259328  (4194304)
//   whalf f16 [1966080]                            @ 9453632  (3932160)
//         [whhf 786432 | whhb 786432 | wihf 196608 | wihb 196608]
//   smallF f32 [71745]                             @ 13385792 (287040)
//         [bihf 1536|bhhf 1536|bihb 1536|bhhb 1536|wlin 65536|blin 64|fg 1]
//   Ycat  f16 [128][128][1024]                     @ 13672832 (33554432)
//   wlinh f16 [64][1024]                           @ 47227264 (131072)
//   wlinl f16 [64][1024]                           @ 47358336 (131072) -> ends 47489408
// ---------------------------------------------------------------------------
#define OFF_SLOT  1048576
#define OFF_FLAG  1064960
#define OFF_XHI   1065024
#define OFF_XLO   5259328
#define OFF_WH    9453632
#define OFF_SMALL 13385792
#define OFF_YCAT  13672832
#define OFF_WLH   47227264
#define OFF_WLL   47358336

// ---------------------------------------------------------------------------
// R20 prep (unchanged from R19): ALL prep fused into ONE dispatch; dtype
// flag computed per-block (deterministic ballot vote over the same 256
// words of Whhf).
//   bid <  7680           : whalf canonicalization (fp16 RTN)
//   bid <  7961           : biases/W_lin/b_lin/forget -> fp32
//   bid <  8217           : W_lin hi/lo f16 planes
//   else (8192 blocks)    : FOFE -> xhi/xlo
// ---------------------------------------------------------------------------
__global__ void prep_all(const void* __restrict__ whhf, const void* __restrict__ whhb,
                         const void* __restrict__ wihf, const void* __restrict__ wihb,
                         const void* __restrict__ bihf, const void* __restrict__ bhhf,
                         const void* __restrict__ bihb, const void* __restrict__ bhhb,
                         const void* __restrict__ wlin, const void* __restrict__ blin,
                         const void* __restrict__ fgp, const int* __restrict__ chars,
                         _Float16* __restrict__ whalf, float* __restrict__ smallF,
                         _Float16* __restrict__ whi, _Float16* __restrict__ wlo,
                         unsigned short* __restrict__ xhi, unsigned short* __restrict__ xlo) {
    const int bid = blockIdx.x;
    const int tid = threadIdx.x;
    const int wave = tid >> 6;
    const int lane = tid & 63;

    // ---- per-block dtype vote (identical inputs -> identical result) ----
    __shared__ int wv[4];
    {
        unsigned word = ((const unsigned*)whhf)[tid];
        unsigned e = (word >> 7) & 0xFFu;
        unsigned long long m = __ballot(e >= 64u && e <= 126u);
        if (lane == 0) wv[wave] = __popcll(m);
    }
    __syncthreads();
    const int fl = (wv[0] + wv[1] + wv[2] + wv[3] >= 160) ? 1 : 0;  // 1 = bf16

    if (bid < 7680) {
        int i = bid * 256 + tid;  // 1966080 exactly
        const void* src;
        int off;
        if (i < 786432)       { src = whhf; off = i; }
        else if (i < 1572864) { src = whhb; off = i - 786432; }
        else if (i < 1769472) { src = wihf; off = i - 1572864; }
        else                  { src = wihb; off = i - 1769472; }
        float v = fl ? __bfloat162float(((const __hip_bfloat16*)src)[off])
                     : ((const float*)src)[off];
        whalf[i] = (_Float16)v;
    } else if (bid < 7961) {
        int i = (bid - 7680) * 256 + tid;
        if (i >= 71745) return;
        const void* src;
        int off;
        if (i < 1536)       { src = bihf; off = i; }
        else if (i < 3072)  { src = bhhf; off = i - 1536; }
        else if (i < 4608)  { src = bihb; off = i - 3072; }
        else if (i < 6144)  { src = bhhb; off = i - 4608; }
        else if (i < 71680) { src = wlin; off = i - 6144; }
        else if (i < 71744) { src = blin; off = i - 71680; }
        else                { src = fgp;  off = 0; }
        float v = fl ? __bfloat162float(((const __hip_bfloat16*)src)[off])
                     : ((const float*)src)[off];
        smallF[i] = v;
    } else if (bid < 8217) {
        int i = (bid - 7961) * 256 + tid;  // 65536
        float v = fl ? __bfloat162float(((const __hip_bfloat16*)wlin)[i])
                     : ((const float*)wlin)[i];
        _Float16 hi = (_Float16)v;
        whi[i] = hi;
        wlo[i] = (_Float16)(v - (float)hi);
    } else {
        // FOFE: 2 positions per block
        __shared__ int cS[2][W_];
        const int fb = bid - 8217;
        int sub = tid >> 7;
        int v = tid & 127;
        int bi = fb * 2 + sub;  // b*S + s
        if (v < W_) cS[sub][v] = chars[bi * W_ + v];
        __syncthreads();
        float f = fl ? __bfloat162float(*(const __hip_bfloat16*)fgp)
                     : *(const float*)fgp;
        float wt[W_];
        float cur = 1.0f;
#pragma unroll
        for (int w = W_ - 1; w >= 0; --w) {
            bool m = (cS[sub][w] != 0);
            wt[w] = m ? cur : 0.0f;
            if (m) cur *= f;
        }
        float acc = 0.0f;
#pragma unroll
        for (int w = 0; w < W_; ++w) acc += (cS[sub][w] == v) ? wt[w] : 0.0f;
        _Float16 hi = (_Float16)acc;
        _Float16 lo = (_Float16)(acc - (float)hi);
        xhi[(size_t)bi * V_ + v] = f16bits(hi);
        xlo[(size_t)bi * V_ + v] = f16bits(lo);
    }
}

// ---------------------------------------------------------------------------
// Persistent bidirectional GRU.
// R20 = R18 champion exchange + x PREFETCHED-TO-LDS ONE STEP AHEAD:
//   - x staging stays COALESCED (R18's tid-based transport — R19's per-lane
//     scatter was the measured -69us regression), but is issued for step
//     t+1 during step t and lands in LDS[1-par] before barrier A(t).
//   - At step t, the 24 x-MFMAs read x(t) from LDS[par] (staged at t-1)
//     BEFORE the volley resolves: they depend only on lgkmcnt, so they
//     execute entirely in the volley's ~1-RT flight shadow.
//   - Ordering: RAW for x(t+1) via barrier A(t); WAR on the x half-row
//     (read at t pre-A(t), rewritten at t+1 post-A(t)) via the same
//     barrier — the R18 double-buffer proof extended to x.
//   - t=0: x(0) staged pre-loop (after lenS barrier) + barrier; t=0 body
//     skips the whole h path (h(0)=0) and keeps one barrier to publish x(1).
//   - Volley/tag protocol, h staging, gates, stores: identical to R18/R19.
// ---------------------------------------------------------------------------
__launch_bounds__(256, 1)
__global__ void gru_kernel(const int* __restrict__ lengths,
                           const _Float16* __restrict__ wh,
                           const float* __restrict__ biasF,
                           const unsigned short* __restrict__ xhi,
                           const unsigned short* __restrict__ xlo,
                           unsigned* __restrict__ hbuf,
                           _Float16* __restrict__ Ycat) {
    constexpr int RSTR = 656;  // 640 + 16 pad halves (0 conflicts measured r5/r7)
    __shared__ _Float16 Ahi[2][16 * RSTR];
    __shared__ _Float16 Alo[2][16 * RSTR];
    __shared__ int lenS[16];

    const int tid = threadIdx.x;
    const int chain = blockIdx.x & 15;
    const int blk = blockIdx.x >> 4;    // 0..7
    const int d = chain & 1;
    const int bg = chain >> 1;
    const int b0 = bg * 16;
    const int wave = tid >> 6;          // 0..3
    const int lane = tid & 63;
    const int quad = lane >> 4;
    const int col = lane & 15;
    const int j0w = (blk * 4 + wave) * 16;  // 0..496

    const _Float16* Whh = wh + (d ? 786432 : 0);
    const _Float16* Wih = wh + 1572864 + (d ? 196608 : 0);
    const float* bih = biasF + (d ? 3072 : 0);
    const float* bhh = biasF + 1536 + (d ? 3072 : 0);

    // x staging: 16 rows x 16 chunks of 8 halves (int4 per plane per thread)
    const int xb = tid >> 4;
    const int xv8 = (tid & 15) * 8;

    if (tid < 16) lenS[tid] = lengths[b0 + tid];
    __syncthreads();

    // ---- pre-loop: stage x(0) into LDS[0] (coalesced) ----
    {
        int lxb = lenS[xb];
        int sx0 = d ? (lxb - 1) : 0;  // lengths >= 1
        *(int4*)&Ahi[0][xb * RSTR + 512 + xv8] =
            *(const int4*)(xhi + ((size_t)(b0 + xb) * S_ + sx0) * V_ + xv8);
        *(int4*)&Alo[0][xb * RSTR + 512 + xv8] =
            *(const int4*)(xlo + ((size_t)(b0 + xb) * S_ + sx0) * V_ + xv8);
    }
    __syncthreads();

    const int g_r = j0w + col;  // r row; z = 512+g_r; n = 1024+g_r

    // Persistent B fragments: lane holds W[g][kk*32 + quad*8 + 0..7]
    f16x8 br[20], bz[20], bn[20];
#pragma unroll
    for (int kk = 0; kk < 16; ++kk) {
        int k = kk * 32 + quad * 8;
        br[kk] = *(const f16x8*)(Whh + (size_t)(g_r)*H_ + k);
        bz[kk] = *(const f16x8*)(Whh + (size_t)(512 + g_r) * H_ + k);
        bn[kk] = *(const f16x8*)(Whh + (size_t)(1024 + g_r) * H_ + k);
    }
#pragma unroll
    for (int kk = 16; kk < 20; ++kk) {
        int k = (kk - 16) * 32 + quad * 8;
        br[kk] = *(const f16x8*)(Wih + (size_t)(g_r)*V_ + k);
        bz[kk] = *(const f16x8*)(Wih + (size_t)(512 + g_r) * V_ + k);
        bn[kk] = *(const f16x8*)(Wih + (size_t)(1024 + g_r) * V_ + k);
    }

    const float bias_r = bih[g_r] + bhh[g_r];
    const float bias_z = bih[512 + g_r] + bhh[512 + g_r];
    const float bihn = bih[1024 + g_r];
    const float bhhn = bhh[1024 + g_r];

    int len4[4];
#pragma unroll
    for (int i = 0; i < 4; ++i) len4[i] = lenS[quad * 4 + i];
    const int maxlen = lenS[0];  // lengths sorted descending

    float h_own[4] = {0.f, 0.f, 0.f, 0.f};  // fp32 master state (b=quad*4+i, j=col)

    const unsigned long long tagMsk = (1ULL << 16) | (1ULL << 48);

    for (int t = 0; t < S_; ++t) {
        if (t < maxlen) {
            const int par = t & 1;
            const _Float16* arh = &Ahi[par][col * RSTR + quad * 8];
            const _Float16* arl = &Alo[par][col * RSTR + quad * 8];

            // ---- coalesced x loads for step t+1 (plain cached; issued first) ----
            const bool doX = (t + 1 < S_);
            int4 xh4 = {0, 0, 0, 0}, xl4 = {0, 0, 0, 0};
            if (doX) {
                int lxb = lenS[xb];
                int sxb = d ? max(0, lxb - 2 - t) : (t + 1);
                xh4 = *(const int4*)(xhi + ((size_t)(b0 + xb) * S_ + sxb) * V_ + xv8);
                xl4 = *(const int4*)(xlo + ((size_t)(b0 + xb) * S_ + sxb) * V_ + xv8);
            }

            // ---- h volley round 1: issue 16 relaxed agent u64 loads ----
            unsigned* hrp = hbuf + ((size_t)(par * 2 + d) * B_ + b0) * H_;
            unsigned long long hv[16];
            if (t > 0) {
#pragma unroll
                for (int i = 0; i < 16; ++i)
                    hv[i] = __hip_atomic_load(
                        (const unsigned long long*)(hrp + (size_t)i * H_ + tid * 2),
                        __ATOMIC_RELAXED, __HIP_MEMORY_SCOPE_AGENT);
            }

            // ---- x-MFMAs from LDS[par] x-region (staged at t-1; lgkmcnt-only,
            //      executes in the volley's flight shadow) ----
            f32x4 accr = {0.f, 0.f, 0.f, 0.f};
            f32x4 accz = {0.f, 0.f, 0.f, 0.f};
            f32x4 acchn = {0.f, 0.f, 0.f, 0.f};
            f32x4 accxn = {0.f, 0.f, 0.f, 0.f};
#pragma unroll
            for (int kx = 0; kx < 4; ++kx) {
                f16x8 ah = *(const f16x8*)(arh + 512 + kx * 32);
                f16x8 al = *(const f16x8*)(arl + 512 + kx * 32);
                accr = __builtin_amdgcn_mfma_f32_16x16x32_f16(ah, br[16 + kx], accr, 0, 0, 0);
                accr = __builtin_amdgcn_mfma_f32_16x16x32_f16(al, br[16 + kx], accr, 0, 0, 0);
                accz = __builtin_amdgcn_mfma_f32_16x16x32_f16(ah, bz[16 + kx], accz, 0, 0, 0);
                accz = __builtin_amdgcn_mfma_f32_16x16x32_f16(al, bz[16 + kx], accz, 0, 0, 0);
                accxn = __builtin_amdgcn_mfma_f32_16x16x32_f16(ah, bn[16 + kx], accxn, 0, 0, 0);
                accxn = __builtin_amdgcn_mfma_f32_16x16x32_f16(al, bn[16 + kx], accxn, 0, 0, 0);
            }

            // ---- stage x(t+1) into LDS[1-par] (before barrier A) ----
            if (doX) {
                *(int4*)&Ahi[1 - par][xb * RSTR + 512 + xv8] = xh4;
                *(int4*)&Alo[1 - par][xb * RSTR + 512 + xv8] = xl4;
            }

            if (t > 0) {
                // ---- volley validate: re-load only stale words ----
                const unsigned te = ((((unsigned)(t - 1)) >> 1) & 1u) ^ 1u;
                const unsigned long long tagPat =
                    ((unsigned long long)te << 16) | ((unsigned long long)te << 48);
                unsigned pend = 0xFFFFu;
                unsigned round = 0;
                while (true) {
                    unsigned np = 0;
#pragma unroll
                    for (int i = 0; i < 16; ++i)
                        if ((pend & (1u << i)) && (hv[i] & tagMsk) != tagPat) np |= (1u << i);
                    if (!np) break;
#pragma unroll
                    for (int i = 0; i < 16; ++i)
                        if (np & (1u << i))
                            hv[i] = __hip_atomic_load(
                                (const unsigned long long*)(hrp + (size_t)i * H_ + tid * 2),
                                __ATOMIC_RELAXED, __HIP_MEMORY_SCOPE_AGENT);
                    pend = np;
                    ++round;
                    if (round > 4u) __builtin_amdgcn_s_sleep(1);
                    if ((round & 31u) == 31u)  // stale-L2 insurance; free if unused
                        __builtin_amdgcn_fence(__ATOMIC_ACQUIRE, "agent");
                    if (round > 400000u) break;  // malfunction -> visible failure
                }

                // ---- unpack h (clear tag bits) and stage into LDS[par] ----
#pragma unroll
                for (int i = 0; i < 16; ++i) {
                    unsigned p0 = (unsigned)hv[i];
                    unsigned p1 = (unsigned)(hv[i] >> 32);
                    unsigned hi2 = (p0 & 0xffffu) | (p1 << 16);
                    unsigned lo2 = ((p0 >> 16) | (p1 & 0xffff0000u)) & ~0x00010001u;
                    *(unsigned*)&Ahi[par][i * RSTR + tid * 2] = hi2;
                    *(unsigned*)&Alo[par][i * RSTR + tid * 2] = lo2;
                }
                __syncthreads();  // A: h(t) + x(t+1) staging visible

                // ---- h-MFMAs ----
#pragma unroll
                for (int kk = 0; kk < 16; ++kk) {
                    f16x8 ah = *(const f16x8*)(arh + kk * 32);
                    f16x8 al = *(const f16x8*)(arl + kk * 32);
                    accr = __builtin_amdgcn_mfma_f32_16x16x32_f16(ah, br[kk], accr, 0, 0, 0);
                    accr = __builtin_amdgcn_mfma_f32_16x16x32_f16(al, br[kk], accr, 0, 0, 0);
                    accz = __builtin_amdgcn_mfma_f32_16x16x32_f16(ah, bz[kk], accz, 0, 0, 0);
                    accz = __builtin_amdgcn_mfma_f32_16x16x32_f16(al, bz[kk], accz, 0, 0, 0);
                    acchn = __builtin_amdgcn_mfma_f32_16x16x32_f16(ah, bn[kk], acchn, 0, 0, 0);
                    acchn = __builtin_amdgcn_mfma_f32_16x16x32_f16(al, bn[kk], acchn, 0, 0, 0);
                }
            } else {
                __syncthreads();  // t=0: publish x(1) staging for t=1 reads
            }

            // ---- gates + state update + tagged h stores (fire-and-forget) ----
            unsigned* hwp = hbuf + ((size_t)((1 - par) * 2 + d) * B_ + b0) * H_;
            const unsigned tg = ((((unsigned)t) >> 1) & 1u) ^ 1u;
            float yv[4];
            int so4[4];
#pragma unroll
            for (int i = 0; i < 4; ++i) {
                int bl = quad * 4 + i;
                float r = sigm(accr[i] + bias_r);
                float zg = sigm(accz[i] + bias_z);
                float ng = tanhf_((accxn[i] + bihn) + r * (acchn[i] + bhhn));
                float hcand = (1.0f - zg) * ng + zg * h_own[i];
                bool m = (t < len4[i]);
                yv[i] = m ? hcand : 0.0f;
                h_own[i] = m ? hcand : h_own[i];
                _Float16 hhi = (_Float16)h_own[i];
                _Float16 hlo = (_Float16)(h_own[i] - (float)hhi);
                unsigned packed = (unsigned)f16bits(hhi) |
                                  ((((unsigned)f16bits(hlo) & 0xFFFEu) | tg) << 16);
                __hip_atomic_store(hwp + (size_t)bl * H_ + j0w + col, packed,
                                   __ATOMIC_RELAXED, __HIP_MEMORY_SCOPE_AGENT);
                so4[i] = (d && m) ? (len4[i] - 1 - t) : t;
            }
            // ---- Ycat stores: drain overlaps peers' polling ----
#pragma unroll
            for (int i = 0; i < 4; ++i) {
                int bl = quad * 4 + i;
                Ycat[((size_t)(b0 + bl) * S_ + so4[i]) * 1024 + d * 512 + j0w + col] =
                    (_Float16)yv[i];
            }
        } else {
            // whole group masked: zeros at s_out = t; no exchange traffic
#pragma unroll
            for (int i = 0; i < 4; ++i) {
                int bl = quad * 4 + i;
                Ycat[((size_t)(b0 + bl) * S_ + t) * 1024 + d * 512 + j0w + col] = (_Float16)0.0f;
            }
        }
    }
}

// ---------------------------------------------------------------------------
// Final linear as MFMA GEMM: out[pos,l] = blin[l] + sum_c Y[pos,c]*W[l,c].
// [16384 x 1024] x [1024 x 64]. Block = 256 thr (4 waves), covers 64 pos;
// wave covers 16 pos x 64 l (4 n-tiles). A-frags load directly from Ycat
// (f16x8, layout = verified GRU operand pattern); W as hi/lo f16 planes
// (exact fp32 reconstruction). 256 MFMA/wave; grid 256.
// ---------------------------------------------------------------------------
__launch_bounds__(256, 1)
__global__ void lin_kernel(const _Float16* __restrict__ Ycat,
                           const _Float16* __restrict__ Whi,
                           const _Float16* __restrict__ Wlo,
                           const float* __restrict__ blinF,
                           float* __restrict__ out) {
    const int tid = threadIdx.x;
    const int wave = tid >> 6;
    const int lane = tid & 63;
    const int quad = lane >> 4;
    const int col = lane & 15;
    const int pos0 = blockIdx.x * 64 + wave * 16;

    const _Float16* arow = Ycat + (size_t)(pos0 + col) * 1024 + quad * 8;

    f32x4 acc[4] = {{0.f, 0.f, 0.f, 0.f}, {0.f, 0.f, 0.f, 0.f},
                    {0.f, 0.f, 0.f, 0.f}, {0.f, 0.f, 0.f, 0.f}};
#pragma unroll 4
    for (int c = 0; c < 1024; c += 32) {
        f16x8 a = *(const f16x8*)(arow + c);
#pragma unroll
        for (int nt = 0; nt < 4; ++nt) {
            const size_t wo = (size_t)(nt * 16 + col) * 1024 + c + quad * 8;
            f16x8 bh = *(const f16x8*)(Whi + wo);
            f16x8 bl = *(const f16x8*)(Wlo + wo);
            acc[nt] = __builtin_amdgcn_mfma_f32_16x16x32_f16(a, bh, acc[nt], 0, 0, 0);
            acc[nt] = __builtin_amdgcn_mfma_f32_16x16x32_f16(a, bl, acc[nt], 0, 0, 0);
        }
    }
    // C layout: row = quad*4 + reg (pos), col = lane&15 (l within n-tile)
#pragma unroll
    for (int nt = 0; nt < 4; ++nt) {
        int l = nt * 16 + col;
        float bias = blinF[l];
#pragma unroll
        for (int r = 0; r < 4; ++r) {
            int pos = pos0 + quad * 4 + r;
            out[(size_t)pos * L_ + l] = acc[nt][r] + bias;
        }
    }
}

extern "C" void kernel_launch(void* const* d_in, const int* in_sizes, int n_in,
                              void* d_out, int out_size, void* d_ws, size_t ws_size,
                              hipStream_t stream) {
    const int* chars = (const int*)d_in[0];
    const int* lengths = (const int*)d_in[1];
    const void* forget = d_in[2];
    const void* Wihf = d_in[3];
    const void* Whhf = d_in[4];
    const void* bihf = d_in[5];
    const void* bhhf = d_in[6];
    const void* Wihb = d_in[7];
    const void* Whhb = d_in[8];
    const void* bihb = d_in[9];
    const void* bhhb = d_in[10];
    const void* Wlin = d_in[11];
    const void* blin = d_in[12];
    float* out = (float*)d_out;

    char* ws = (char*)d_ws;
    unsigned* hbuf = (unsigned*)(ws + 0);
    unsigned short* xhi = (unsigned short*)(ws + OFF_XHI);
    unsigned short* xlo = (unsigned short*)(ws + OFF_XLO);
    _Float16* whalf = (_Float16*)(ws + OFF_WH);
    float* smallF = (float*)(ws + OFF_SMALL);
    _Float16* Ycat = (_Float16*)(ws + OFF_YCAT);
    _Float16* wlh = (_Float16*)(ws + OFF_WLH);
    _Float16* wll = (_Float16*)(ws + OFF_WLL);

    // zero h state only (both parities, tag bits = 0)
    (void)hipMemsetAsync(ws, 0, 1048576, stream);

    // fused prep: whalf (7680) + small (281) + wlin planes (256) + fofe (8192)
    hipLaunchKernelGGL(prep_all, dim3(16409), dim3(256), 0, stream,
                       Whhf, Whhb, Wihf, Wihb, bihf, bhhf, bihb, bhhb,
                       Wlin, blin, forget, chars,
                       whalf, smallF, wlh, wll, xhi, xlo);

    // 16 chains x 8 blocks x 256 threads; tagged fire-and-forget exchange.
    hipLaunchKernelGGL(gru_kernel, dim3(128), dim3(256), 0, stream,
                       lengths, whalf, smallF, xhi, xlo, hbuf, Ycat);

    // MFMA GEMM epilogue: 256 blocks x 64 pos.
    hipLaunchKernelGGL(lin_kernel, dim3(256), dim3(256), 0, stream,
                       Ycat, wlh, wll, smallF + 71680, out);
}